// Round 1
// 1145.662 us; speedup vs baseline: 1.0283x; 1.0283x over previous
//
#include <hip/hip_runtime.h>

#define NHID 256

typedef __attribute__((ext_vector_type(8))) short short8;
typedef __attribute__((ext_vector_type(4))) float floatx4;
typedef __attribute__((ext_vector_type(4))) float float4v;
typedef __attribute__((ext_vector_type(4))) int int4v;
typedef __attribute__((ext_vector_type(4))) unsigned int uint4v;

static __device__ __forceinline__ short f2bf(float f) {
    unsigned u = __float_as_uint(f);
    unsigned r = (u + 0x7fffu + ((u >> 16) & 1u)) >> 16;
    return (short)r;
}
static __device__ __forceinline__ unsigned pk2(float a, float b) {
    return ((unsigned)(unsigned short)f2bf(a)) | (((unsigned)(unsigned short)f2bf(b)) << 16);
}

// ---------------- W transpose+cast: Wt[n][k] bf16 from W[k][n] fp32 ----------------
__global__ void transpose_cast(const float* __restrict__ W, short* __restrict__ Wt, int K)
{
    int idx = blockIdx.x * 256 + threadIdx.x;
    if (idx >= K * NHID) return;
    int k = idx >> 8;
    int n = idx & 255;
    Wt[(size_t)n * K + k] = f2bf(W[idx]);
}

// ---------------- MFMA GEMM: C[M x 256](bf16) = A[M x K] @ Bt[n][k](bf16) ----------
// BN = 256 (full width): A is read exactly once. 512 threads, 8 waves (2x4).
template<bool ABF16>
__global__ __launch_bounds__(512) void gemm_mfma(
    const void* __restrict__ Ap, const short* __restrict__ Bt,
    short* __restrict__ C, int M, int K)
{
    __shared__ __align__(16) short As[128][40];
    __shared__ __align__(16) short Bs[256][40];

    int tid  = threadIdx.x;
    int m0   = blockIdx.x * 128;
    int lane = tid & 63;
    int wid  = tid >> 6;      // 0..7
    int wm   = wid >> 2;      // 0..1 : 64-row block
    int wn   = wid & 3;       // 0..3 : 64-col block
    int quad = lane >> 4;
    int l16  = lane & 15;

    floatx4 acc[4][4] = {};

    for (int k0 = 0; k0 < K; k0 += 32) {
        if (ABF16) {
            const short* A = (const short*)Ap;
            int tr = tid >> 2, tc = (tid & 3) * 8;      // 128 rows x 32 cols
            int gm = m0 + tr;
            int4v v = {0, 0, 0, 0};
            if (gm < M) v = __builtin_nontemporal_load((const int4v*)(A + (size_t)gm * K + k0 + tc));
            *(int4v*)&As[tr][tc] = v;
        } else {
            const float* A = (const float*)Ap;
            int tr = tid >> 3, tc = (tid & 7) * 4;      // 64 rows per pass
            #pragma unroll
            for (int p = 0; p < 2; ++p) {
                int m = p * 64 + tr, gm = m0 + m;
                float4v v = {0.f, 0.f, 0.f, 0.f};
                if (gm < M) v = __builtin_nontemporal_load((const float4v*)(A + (size_t)gm * K + k0 + tc));
                short4 s;
                s.x = f2bf(v.x); s.y = f2bf(v.y); s.z = f2bf(v.z); s.w = f2bf(v.w);
                *(short4*)&As[m][tc] = s;
            }
        }
        {
            int nr = tid >> 2, nc = (tid & 3) * 8;      // 128 rows per pass
            #pragma unroll
            for (int p = 0; p < 2; ++p) {
                int n = p * 128 + nr;
                *(int4*)&Bs[n][nc] = *(const int4*)(Bt + (size_t)n * K + k0 + nc);
            }
        }
        __syncthreads();

        short8 af[4], bfr[4];
        #pragma unroll
        for (int t = 0; t < 4; ++t) {
            af[t]  = *(const short8*)&As[wm * 64 + t * 16 + l16][quad * 8];
            bfr[t] = *(const short8*)&Bs[wn * 64 + t * 16 + l16][quad * 8];
        }
        #pragma unroll
        for (int tm = 0; tm < 4; ++tm)
            #pragma unroll
            for (int tn = 0; tn < 4; ++tn)
                acc[tm][tn] = __builtin_amdgcn_mfma_f32_16x16x32_bf16(
                    af[tm], bfr[tn], acc[tm][tn], 0, 0, 0);
        __syncthreads();
    }

    #pragma unroll
    for (int tm = 0; tm < 4; ++tm) {
        #pragma unroll
        for (int r = 0; r < 4; ++r) {
            int row = m0 + wm * 64 + tm * 16 + quad * 4 + r;
            if (row < M) {
                #pragma unroll
                for (int tn = 0; tn < 4; ++tn) {
                    int col = wn * 64 + tn * 16 + l16;
                    C[(size_t)row * NHID + col] = f2bf(acc[tm][tn][r]);
                }
            }
        }
    }
}

// ---------------- CSR build ----------------
__global__ void hist_kernel(const int* __restrict__ rows, int* __restrict__ counts, int E)
{
    int i = blockIdx.x * blockDim.x + threadIdx.x;
    if (i < E) atomicAdd(&counts[rows[i]], 1);
}

__global__ __launch_bounds__(256) void block_scan(
    const int* __restrict__ counts, int* __restrict__ tmp, int* __restrict__ bsum, int n)
{
    __shared__ int ws[4];
    int tid = threadIdx.x, b = blockIdx.x;
    int i = b * 256 + tid;
    int lane = tid & 63, w = tid >> 6;
    int v = (i < n) ? counts[i] : 0;
    int x = v;
    #pragma unroll
    for (int off = 1; off < 64; off <<= 1) {
        int y = __shfl_up(x, off, 64);
        if (lane >= off) x += y;
    }
    if (lane == 63) ws[w] = x;
    __syncthreads();
    int add = 0;
    #pragma unroll
    for (int k = 0; k < 4; ++k) if (k < w) add += ws[k];
    x += add;
    if (i < n) tmp[i] = x;
    if (tid == 255) bsum[b] = x;
}

__global__ __launch_bounds__(256) void scan_bsums(int* __restrict__ bsum, int nb)
{
    __shared__ int ws[4];
    __shared__ int carry;
    int tid = threadIdx.x, lane = tid & 63, w = tid >> 6;
    if (tid == 0) carry = 0;
    __syncthreads();
    for (int base = 0; base < nb; base += 256) {
        int i = base + tid;
        int v = (i < nb) ? bsum[i] : 0;
        int x = v;
        #pragma unroll
        for (int off = 1; off < 64; off <<= 1) {
            int y = __shfl_up(x, off, 64);
            if (lane >= off) x += y;
        }
        if (lane == 63) ws[w] = x;
        __syncthreads();
        int add = 0;
        #pragma unroll
        for (int k = 0; k < 4; ++k) if (k < w) add += ws[k];
        int incl = x + add;
        int c = carry;
        if (i < nb) bsum[i] = incl - v + c;   // exclusive prefix
        __syncthreads();
        if (tid == 255) carry = c + incl;
        __syncthreads();
    }
}

__global__ void finalize_scan(const int* __restrict__ tmp, const int* __restrict__ boff,
                              int* __restrict__ row_ptr, int n)
{
    int i = blockIdx.x * 256 + threadIdx.x;
    if (i < n) row_ptr[i + 1] = tmp[i] + boff[i >> 8];
    if (i == 0) row_ptr[0] = 0;
}

__global__ void scatter_kernel(
    const int* __restrict__ erow, const int* __restrict__ ecol,
    const float* __restrict__ eval, const int* __restrict__ row_ptr,
    int* __restrict__ fill, int2* __restrict__ ep, int E)
{
    int i = blockIdx.x * blockDim.x + threadIdx.x;
    if (i < E) {
        int r = erow[i];
        int p = row_ptr[r] + atomicAdd(&fill[r], 1);
        ep[p] = make_int2(ecol[i], __float_as_int(eval[i]));
    }
}

// ---------------- SpMM: split-wave, 16B gathers, packed edges, bias+PReLU ----------
static __device__ __forceinline__ void fma8(float* acc, uint4 g, float v)
{
    acc[0] += v * __uint_as_float(g.x << 16);
    acc[1] += v * __uint_as_float(g.x & 0xffff0000u);
    acc[2] += v * __uint_as_float(g.y << 16);
    acc[3] += v * __uint_as_float(g.y & 0xffff0000u);
    acc[4] += v * __uint_as_float(g.z << 16);
    acc[5] += v * __uint_as_float(g.z & 0xffff0000u);
    acc[6] += v * __uint_as_float(g.w << 16);
    acc[7] += v * __uint_as_float(g.w & 0xffff0000u);
}

// nontemporal 8B edge load (keeps the 25.6 MB ep stream out of L3)
static __device__ __forceinline__ int2 ld_ep(const int2* p)
{
    long long t = __builtin_nontemporal_load((const long long*)p);
    int2 r;
    r.x = (int)(t & 0xffffffffLL);
    r.y = (int)(t >> 32);
    return r;
}

template<bool OUT_BF16>
__global__ __launch_bounds__(256) void spmm_split(
    const int* __restrict__ row_ptr, const int2* __restrict__ ep,
    const short* __restrict__ dense,
    const float* __restrict__ bias, const float* __restrict__ alpha_p,
    void* __restrict__ outp, int nrows)
{
    int wid  = (blockIdx.x * blockDim.x + threadIdx.x) >> 6;
    int lane = threadIdx.x & 63;
    if (wid >= nrows) return;
    int half = lane >> 5;
    int l32  = lane & 31;
    int s = row_ptr[wid], e = row_ptr[wid + 1];
    int fo = l32 * 8;                       // bf16 elem offset; 16 B per lane

    float acc[8] = {};
    int i = s;
    for (; i + 7 < e; i += 8) {             // 8 edges per iter, 4 per half
        int2 e0 = ld_ep(&ep[i + half]);
        int2 e1 = ld_ep(&ep[i + 2 + half]);
        int2 e2 = ld_ep(&ep[i + 4 + half]);
        int2 e3 = ld_ep(&ep[i + 6 + half]);
        uint4 g0 = *(const uint4*)(dense + (size_t)e0.x * NHID + fo);
        uint4 g1 = *(const uint4*)(dense + (size_t)e1.x * NHID + fo);
        uint4 g2 = *(const uint4*)(dense + (size_t)e2.x * NHID + fo);
        uint4 g3 = *(const uint4*)(dense + (size_t)e3.x * NHID + fo);
        fma8(acc, g0, __int_as_float(e0.y));
        fma8(acc, g1, __int_as_float(e1.y));
        fma8(acc, g2, __int_as_float(e2.y));
        fma8(acc, g3, __int_as_float(e3.y));
    }
    for (; i + 3 < e; i += 4) {             // 4 edges per iter, 2 per half
        int2 e0 = ld_ep(&ep[i + half]);
        int2 e1 = ld_ep(&ep[i + 2 + half]);
        uint4 g0 = *(const uint4*)(dense + (size_t)e0.x * NHID + fo);
        uint4 g1 = *(const uint4*)(dense + (size_t)e1.x * NHID + fo);
        fma8(acc, g0, __int_as_float(e0.y));
        fma8(acc, g1, __int_as_float(e1.y));
    }
    for (; i < e; i += 2) {                 // remainder (0..3 edges)
        int j = i + half;
        if (j < e) {
            int2 e0 = ld_ep(&ep[j]);
            uint4 g0 = *(const uint4*)(dense + (size_t)e0.x * NHID + fo);
            fma8(acc, g0, __int_as_float(e0.y));
        }
    }

    #pragma unroll
    for (int k = 0; k < 8; ++k) acc[k] += __shfl_xor(acc[k], 32, 64);

    float alpha = alpha_p[0];
    float4 b0 = *(const float4*)(bias + fo);
    float4 b1 = *(const float4*)(bias + fo + 4);
    float r[8];
    r[0] = acc[0] + b0.x; r[1] = acc[1] + b0.y; r[2] = acc[2] + b0.z; r[3] = acc[3] + b0.w;
    r[4] = acc[4] + b1.x; r[5] = acc[5] + b1.y; r[6] = acc[6] + b1.z; r[7] = acc[7] + b1.w;
    #pragma unroll
    for (int k = 0; k < 8; ++k) r[k] = (r[k] >= 0.f) ? r[k] : alpha * r[k];

    if (OUT_BF16) {
        if (half == 0) {
            uint4v o;
            o.x = pk2(r[0], r[1]); o.y = pk2(r[2], r[3]);
            o.z = pk2(r[4], r[5]); o.w = pk2(r[6], r[7]);
            __builtin_nontemporal_store(o, (uint4v*)((short*)outp + (size_t)wid * NHID + fo));
        }
    } else {
        float4v ov;
        if (half) { ov.x = r[4]; ov.y = r[5]; ov.z = r[6]; ov.w = r[7]; }
        else      { ov.x = r[0]; ov.y = r[1]; ov.z = r[2]; ov.w = r[3]; }
        __builtin_nontemporal_store(ov, (float4v*)((float*)outp + (size_t)wid * NHID + fo + half * 4));
    }
}

extern "C" void kernel_launch(void* const* d_in, const int* in_sizes, int n_in,
                              void* d_out, int out_size, void* d_ws, size_t ws_size,
                              hipStream_t stream)
{
    const float* x     = (const float*)d_in[0];
    const int*   erow  = (const int*)d_in[1];
    const int*   ecol  = (const int*)d_in[2];
    const float* eval  = (const float*)d_in[3];
    const float* W1    = (const float*)d_in[4];
    const float* b1    = (const float*)d_in[5];
    const float* W2    = (const float*)d_in[6];
    const float* b2    = (const float*)d_in[7];
    const float* alpha = (const float*)d_in[8];

    int NFEAT = 512;
    int N = in_sizes[0] / NFEAT;   // 100000
    int E = in_sizes[1];           // 3200000
    float* out = (float*)d_out;

    // Workspace layout (~128.8 MB)
    char* wsp = (char*)d_ws;
    short* support_b = (short*)wsp;  wsp += (size_t)N * NHID * sizeof(short);  // 51.2 MB
    short* h1b       = (short*)wsp;  wsp += (size_t)N * NHID * sizeof(short);  // 51.2 MB
    int2*  ep        = (int2*)wsp;   wsp += (size_t)E * sizeof(int2);          // 25.6 MB
    int*   row_ptr   = (int*)wsp;    wsp += ((size_t)(N + 1) * sizeof(int) + 15) & ~(size_t)15;
    short* W1t       = (short*)wsp;  wsp += (size_t)NFEAT * NHID * sizeof(short);
    short* W2t       = (short*)wsp;  wsp += (size_t)NHID * NHID * sizeof(short);

    // scratch aliased into h1b (dead until spmm1 writes it)
    int* fill = (int*)h1b;
    int* tmp  = fill + N;
    int* bsum = tmp + N;
    int  nblk = (N + 255) / 256;

    // ---- Weight transpose+cast ----
    transpose_cast<<<(NFEAT * NHID + 255) / 256, 256, 0, stream>>>(W1, W1t, NFEAT);
    transpose_cast<<<(NHID * NHID + 255) / 256, 256, 0, stream>>>(W2, W2t, NHID);

    // ---- CSR build ----
    hipMemsetAsync(fill, 0, (size_t)N * sizeof(int), stream);
    hist_kernel<<<(E + 255) / 256, 256, 0, stream>>>(erow, fill, E);
    block_scan<<<nblk, 256, 0, stream>>>(fill, tmp, bsum, N);
    scan_bsums<<<1, 256, 0, stream>>>(bsum, nblk);
    finalize_scan<<<nblk, 256, 0, stream>>>(tmp, bsum, row_ptr, N);
    hipMemsetAsync(fill, 0, (size_t)N * sizeof(int), stream);
    scatter_kernel<<<(E + 255) / 256, 256, 0, stream>>>(erow, ecol, eval, row_ptr, fill, ep, E);

    int  ggrid = (N + 127) / 128;
    int  spmm_blocks = (N + 3) / 4;

    // ---- Layer 1 ----
    gemm_mfma<false><<<ggrid, 512, 0, stream>>>(x, W1t, support_b, N, NFEAT);
    spmm_split<true><<<spmm_blocks, 256, 0, stream>>>(row_ptr, ep, support_b, b1, alpha, h1b, N);
    // ---- Layer 2 ----
    gemm_mfma<true><<<ggrid, 512, 0, stream>>>(h1b, W2t, support_b, N, NHID);
    spmm_split<false><<<spmm_blocks, 256, 0, stream>>>(row_ptr, ep, support_b, b2, alpha, out, N);
}